// Round 11
// baseline (47.937 us; speedup 1.0000x reference)
//
#include <hip/hip_runtime.h>

// DepthLossForImgBEV: weighted BCE over (B,N,D,H,W) depth logits vs one-hot
// bucketized GT depth, reduced to a scalar mean * 3.0.
//
// MEASUREMENT ROUND (R11): k1 and k2 are byte-identical to R10 (20.56 us),
// but the graph launches k1 THREE times (idempotent; writes the same partials
// each time) + k2 once.  dur = 3*k1 + k2 + 4*gap, so
//   k1 + gap = (dur_R11 - 20.56) / 2.
// This finally splits the stable ~20.5 us into k1 vs k2+overhead -- the
// rocprof top-5 is always hidden by the harness's ~39 us poison fills, so
// k1's duration has never been directly observed.
//
// Standing facts: two-dispatch variants are geometry-insensitive (20.5-22 us
// across R2/R4/R7/R10); fused single-dispatch dies to VGPR collapse (R3/R9);
// in-graph 4B memsets cost ~20 us (R1 vs R2) so ticket schemes are dead.
// k1 floor: ~31.5 MB HBM + ~30 MB L3-resident => ~7-8 us memory, ~2.5 us VALU.

namespace {

constexpr int B_ = 2, N_ = 6, D_ = 112, H_ = 64, W_ = 176;
constexpr int HW_   = H_ * W_;          // 11264
constexpr int NHWQ_ = HW_ / 4;          // 2816 float4 quads per image plane
constexpr int DPC_  = 16, NCH_ = 7;     // 7 d-chunks x 16 slices = 112
constexpr int NBN_  = B_ * N_;          // 12
constexpr long long TOT_ = (long long)NBN_ * D_ * HW_;   // 15,138,816
constexpr int NTHR_ = NBN_ * NCH_ * NHWQ_;               // 236,544
constexpr int NBLK_ = NTHR_ / 256;                       // 924 blocks
constexpr float SCALE_ = (float)(3.0 / (double)TOT_);    // 3.0 / numel

// bce = min(softplus(+-x), 100) * w;  softplus(x) = relu(x) + log1p(exp(-|x|))
__device__ __forceinline__ float term(float x, float w, bool hit) {
    float c = __logf(1.0f + __expf(-fabsf(x)));          // shared log term
    float r = hit ? fmaxf(-x, 0.0f) : fmaxf(x, 0.0f);
    return w * fminf(c + r, 100.0f);
}

__device__ __forceinline__ int bucket(float g) {
    int i = (int)floorf((g - 2.0f) * 2.0f);   // (g - DBOUND0) / DBOUND2
    return i < 0 ? 0 : (i > D_ ? D_ : i);     // clip [0,D]; D never matches d
}

__global__ __launch_bounds__(256) void depth_loss_part(
        const float* __restrict__ gt, const float* __restrict__ dp,
        float* __restrict__ part) {
    const int t    = blockIdx.x * 256 + threadIdx.x;
    const int hwq  = t % NHWQ_;           // quad within image plane
    const int rest = t / NHWQ_;
    const int ch   = rest % NCH_;         // which 16-slice d-chunk
    const int bn   = rest / NCH_;         // (b*N + n)
    const int hw   = hwq * 4;
    const int d0   = ch * DPC_;

    // issue gt + all 16 slice loads back-to-back
    const float4 g = *reinterpret_cast<const float4*>(gt + bn * HW_ + hw);
    const float* p = dp + ((bn * D_ + d0) * HW_ + hw);
    float4 xv[DPC_];
    #pragma unroll
    for (int i = 0; i < DPC_; ++i)
        xv[i] = *reinterpret_cast<const float4*>(p + (size_t)i * HW_);

    // keep-alive fence (R10; neutral but harmless -- keeps loads batched)
    #pragma unroll
    for (int i = 0; i < DPC_; ++i)
        asm volatile("" :: "v"(xv[i].x), "v"(xv[i].y), "v"(xv[i].z), "v"(xv[i].w));

    const float w0 = (g.x != 0.0f) ? 1.0f : 0.0f;
    const float w1 = (g.y != 0.0f) ? 1.0f : 0.0f;
    const float w2 = (g.z != 0.0f) ? 1.0f : 0.0f;
    const float w3 = (g.w != 0.0f) ? 1.0f : 0.0f;
    const int  i0 = bucket(g.x), i1 = bucket(g.y), i2 = bucket(g.z), i3 = bucket(g.w);

    float s = 0.0f;
    #pragma unroll
    for (int i = 0; i < DPC_; ++i) {
        const int d = d0 + i;
        s += term(xv[i].x, w0, d == i0);
        s += term(xv[i].y, w1, d == i1);
        s += term(xv[i].z, w2, d == i2);
        s += term(xv[i].w, w3, d == i3);
    }

    // block reduce -> one partial per block (overwrite, no init needed)
    #pragma unroll
    for (int off = 32; off > 0; off >>= 1) s += __shfl_down(s, off, 64);
    __shared__ float ls[4];
    if ((threadIdx.x & 63) == 0) ls[threadIdx.x >> 6] = s;
    __syncthreads();
    if (threadIdx.x == 0)
        part[blockIdx.x] = (ls[0] + ls[1]) + (ls[2] + ls[3]);
}

__global__ __launch_bounds__(256) void depth_loss_final(
        const float* __restrict__ part, float* __restrict__ out) {
    float s = part[threadIdx.x] + part[threadIdx.x + 256] + part[threadIdx.x + 512];
    if (threadIdx.x + 768 < NBLK_) s += part[threadIdx.x + 768];
    #pragma unroll
    for (int off = 32; off > 0; off >>= 1) s += __shfl_down(s, off, 64);
    __shared__ float ls[4];
    if ((threadIdx.x & 63) == 0) ls[threadIdx.x >> 6] = s;
    __syncthreads();
    if (threadIdx.x == 0)
        out[0] = ((ls[0] + ls[1]) + (ls[2] + ls[3])) * SCALE_;
}

}  // namespace

extern "C" void kernel_launch(void* const* d_in, const int* in_sizes, int n_in,
                              void* d_out, int out_size, void* d_ws, size_t ws_size,
                              hipStream_t stream) {
    const float* gt = (const float*)d_in[0];   // depth_gt (B,N,H,W)
    const float* dp = (const float*)d_in[1];   // depth (B,N*D,H,W)
    float* part = (float*)d_ws;                // 924 floats of scratch
    float* out  = (float*)d_out;
    // 3x k1 (idempotent) + k2: dur = 3*k1 + k2 + 4*gap  ->  solve for k1+gap.
    depth_loss_part<<<NBLK_, 256, 0, stream>>>(gt, dp, part);
    depth_loss_part<<<NBLK_, 256, 0, stream>>>(gt, dp, part);
    depth_loss_part<<<NBLK_, 256, 0, stream>>>(gt, dp, part);
    depth_loss_final<<<1, 256, 0, stream>>>(part, out);
}

// Round 12
// 46.380 us; speedup vs baseline: 1.0336x; 1.0336x over previous
//
#include <hip/hip_runtime.h>

// DepthLossForImgBEV: weighted BCE over (B,N,D,H,W) depth logits vs one-hot
// bucketized GT depth, reduced to a scalar mean * 3.0.
//
// B=2 N=6 D=112 H=64 W=176.  depth: (B,N*D,H,W) f32 (60.6 MB, ~half
// L3-resident); depth_gt: (B,N,H,W) f32 (cache-hot).
//
// R11 measurement: k1 ~= 12 us, k2 + dispatch overhead ~= 7 us of the 20.56.
// R12: single dispatch, no memset, no coop. Completion via a 924-entry flag
// array in d_ws: each block (1) agent-scope-stores its partial (write-through
// to the coherent point -- per-XCD L2s are NOT coherent), (2) release-stores
// MAGIC to flags[bid], (3) scans all flags. Any block seeing all-set is a
// finisher: acquire fence -> fixed-order reduce -> out; then clears flags.
// >=1 finisher guaranteed (the last setter sees all-set); multiple finishers
// write the identical value (benign); correct from ANY initial flags content
// (poison/garbage) since blocks set-before-scan; partials are replay-
// invariant so stale-flag races are also benign.
// k1 body is byte-identical to R10 (20.56 us), incl. the keep-alive fence --
// which also guards against the fused-tail VGPR collapse (R3: 16, R9: 32).

namespace {

constexpr int B_ = 2, N_ = 6, D_ = 112, H_ = 64, W_ = 176;
constexpr int HW_   = H_ * W_;          // 11264
constexpr int NHWQ_ = HW_ / 4;          // 2816 float4 quads per image plane
constexpr int DPC_  = 16, NCH_ = 7;     // 7 d-chunks x 16 slices = 112
constexpr int NBN_  = B_ * N_;          // 12
constexpr long long TOT_ = (long long)NBN_ * D_ * HW_;   // 15,138,816
constexpr int NTHR_ = NBN_ * NCH_ * NHWQ_;               // 236,544
constexpr int NBLK_ = NTHR_ / 256;                       // 924 blocks
constexpr float SCALE_ = (float)(3.0 / (double)TOT_);    // 3.0 / numel
constexpr int MAGIC_ = 0x5A17ED0F;

// bce = min(softplus(+-x), 100) * w;  softplus(x) = relu(x) + log1p(exp(-|x|))
__device__ __forceinline__ float term(float x, float w, bool hit) {
    float c = __logf(1.0f + __expf(-fabsf(x)));          // shared log term
    float r = hit ? fmaxf(-x, 0.0f) : fmaxf(x, 0.0f);
    return w * fminf(c + r, 100.0f);
}

__device__ __forceinline__ int bucket(float g) {
    int i = (int)floorf((g - 2.0f) * 2.0f);   // (g - DBOUND0) / DBOUND2
    return i < 0 ? 0 : (i > D_ ? D_ : i);     // clip [0,D]; D never matches d
}

__global__ __launch_bounds__(256) void depth_loss_fused(
        const float* __restrict__ gt, const float* __restrict__ dp,
        float* __restrict__ part, int* __restrict__ flags,
        float* __restrict__ out) {
    const int t    = blockIdx.x * 256 + threadIdx.x;
    const int hwq  = t % NHWQ_;           // quad within image plane
    const int rest = t / NHWQ_;
    const int ch   = rest % NCH_;         // which 16-slice d-chunk
    const int bn   = rest / NCH_;         // (b*N + n)
    const int hw   = hwq * 4;
    const int d0   = ch * DPC_;

    // issue gt + all 16 slice loads back-to-back
    const float4 g = *reinterpret_cast<const float4*>(gt + bn * HW_ + hw);
    const float* p = dp + ((bn * D_ + d0) * HW_ + hw);
    float4 xv[DPC_];
    #pragma unroll
    for (int i = 0; i < DPC_; ++i)
        xv[i] = *reinterpret_cast<const float4*>(p + (size_t)i * HW_);

    // keep-alive fence: forces the 16 float4s live -> loads stay batched and
    // the fused tail cannot trigger the low-VGPR serialization (R3/R9).
    #pragma unroll
    for (int i = 0; i < DPC_; ++i)
        asm volatile("" :: "v"(xv[i].x), "v"(xv[i].y), "v"(xv[i].z), "v"(xv[i].w));

    const float w0 = (g.x != 0.0f) ? 1.0f : 0.0f;
    const float w1 = (g.y != 0.0f) ? 1.0f : 0.0f;
    const float w2 = (g.z != 0.0f) ? 1.0f : 0.0f;
    const float w3 = (g.w != 0.0f) ? 1.0f : 0.0f;
    const int  i0 = bucket(g.x), i1 = bucket(g.y), i2 = bucket(g.z), i3 = bucket(g.w);

    float s = 0.0f;
    #pragma unroll
    for (int i = 0; i < DPC_; ++i) {
        const int d = d0 + i;
        s += term(xv[i].x, w0, d == i0);
        s += term(xv[i].y, w1, d == i1);
        s += term(xv[i].z, w2, d == i2);
        s += term(xv[i].w, w3, d == i3);
    }

    // block reduce -> one partial per block
    #pragma unroll
    for (int off = 32; off > 0; off >>= 1) s += __shfl_down(s, off, 64);
    __shared__ float ls[4];
    if ((threadIdx.x & 63) == 0) ls[threadIdx.x >> 6] = s;
    __syncthreads();
    if (threadIdx.x == 0) {
        // partial write-through to the coherent point, then publish flag
        __hip_atomic_store(&part[blockIdx.x], (ls[0] + ls[1]) + (ls[2] + ls[3]),
                           __ATOMIC_RELAXED, __HIP_MEMORY_SCOPE_AGENT);
        __hip_atomic_store(&flags[blockIdx.x], MAGIC_,
                           __ATOMIC_RELEASE, __HIP_MEMORY_SCOPE_AGENT);
    }
    __syncthreads();

    // completion scan: <=4 relaxed agent loads per thread
    bool ok = true;
    for (int i = threadIdx.x; i < NBLK_; i += 256)
        ok &= (__hip_atomic_load(&flags[i], __ATOMIC_RELAXED,
                                 __HIP_MEMORY_SCOPE_AGENT) == MAGIC_);
    unsigned long long vote = __ballot(ok);
    __shared__ int wok[4];
    if ((threadIdx.x & 63) == 0) wok[threadIdx.x >> 6] = (vote == ~0ull);
    __syncthreads();
    const bool allset = wok[0] && wok[1] && wok[2] && wok[3];

    if (allset) {   // finisher(s): all 924 partials are published
        __threadfence();   // acquire side: order flag reads -> partial reads
        float r = 0.0f;
        for (int i = threadIdx.x; i < NBLK_; i += 256)
            r += __hip_atomic_load(&part[i], __ATOMIC_RELAXED,
                                   __HIP_MEMORY_SCOPE_AGENT);
        #pragma unroll
        for (int off = 32; off > 0; off >>= 1) r += __shfl_down(r, off, 64);
        if ((threadIdx.x & 63) == 0) ls[threadIdx.x >> 6] = r;
        __syncthreads();
        if (threadIdx.x == 0)
            out[0] = ((ls[0] + ls[1]) + (ls[2] + ls[3])) * SCALE_;
        // clear flags for the next replay (idempotent across finishers)
        for (int i = threadIdx.x; i < NBLK_; i += 256)
            __hip_atomic_store(&flags[i], 0, __ATOMIC_RELAXED,
                               __HIP_MEMORY_SCOPE_AGENT);
    }
}

}  // namespace

extern "C" void kernel_launch(void* const* d_in, const int* in_sizes, int n_in,
                              void* d_out, int out_size, void* d_ws, size_t ws_size,
                              hipStream_t stream) {
    const float* gt = (const float*)d_in[0];   // depth_gt (B,N,H,W)
    const float* dp = (const float*)d_in[1];   // depth (B,N*D,H,W)
    float* part = (float*)d_ws;                // 924 floats @ ws+0
    int* flags  = (int*)((char*)d_ws + 4096);  // 924 ints  @ ws+4096
    float* out  = (float*)d_out;
    depth_loss_fused<<<NBLK_, 256, 0, stream>>>(gt, dp, part, flags, out);
}

// Round 13
// 34.998 us; speedup vs baseline: 1.3697x; 1.3252x over previous
//
#include <hip/hip_runtime.h>

// DepthLossForImgBEV: weighted BCE over (B,N,D,H,W) depth logits vs one-hot
// bucketized GT depth, reduced to a scalar mean * 3.0.
//
// B=2 N=6 D=112 H=64 W=176.  depth: (B,N*D,H,W) f32 (60.6 MB, ~half
// L3-resident); depth_gt: (B,N,H,W) f32 (cache-hot).
//
// R11 measured: k1 ~= 12 us, k2 + dispatch gap ~= 7 us. R12's fused
// all-blocks-scan-all-flags was O(N^2) agent-scope contention (~854K
// coherent loads): L3-hot replays still took ~54 us. In-graph 4B memsets
// cost ~39 us/dispatch (R1 counters) -> ticket schemes needing zeroing dead.
//
// R13: single dispatch, O(N) completion. Non-finishers: agent-store partial,
// release-store flags[bid], EXIT (no scanning). Block 0 only: poll own <=4
// flags/thread with s_sleep backoff + __syncthreads_and until all 923 peers
// published; acquire fence; fixed-order reduce of 924 partials; write out;
// clear flags (ordered before kernel-end release -> next replay clean).
// First call: flags are fresh-alloc/0xAA poison != MAGIC -> no false finish.
// No deadlock: block 0 holds one CU slot; others drain freely.

namespace {

constexpr int B_ = 2, N_ = 6, D_ = 112, H_ = 64, W_ = 176;
constexpr int HW_   = H_ * W_;          // 11264
constexpr int NHWQ_ = HW_ / 4;          // 2816 float4 quads per image plane
constexpr int DPC_  = 16, NCH_ = 7;     // 7 d-chunks x 16 slices = 112
constexpr int NBN_  = B_ * N_;          // 12
constexpr long long TOT_ = (long long)NBN_ * D_ * HW_;   // 15,138,816
constexpr int NTHR_ = NBN_ * NCH_ * NHWQ_;               // 236,544
constexpr int NBLK_ = NTHR_ / 256;                       // 924 blocks
constexpr float SCALE_ = (float)(3.0 / (double)TOT_);    // 3.0 / numel
constexpr int MAGIC_ = 0x5A17ED0F;      // != 0, != 0xAAAAAAAA

// bce = min(softplus(+-x), 100) * w;  softplus(x) = relu(x) + log1p(exp(-|x|))
__device__ __forceinline__ float term(float x, float w, bool hit) {
    float c = __logf(1.0f + __expf(-fabsf(x)));          // shared log term
    float r = hit ? fmaxf(-x, 0.0f) : fmaxf(x, 0.0f);
    return w * fminf(c + r, 100.0f);
}

__device__ __forceinline__ int bucket(float g) {
    int i = (int)floorf((g - 2.0f) * 2.0f);   // (g - DBOUND0) / DBOUND2
    return i < 0 ? 0 : (i > D_ ? D_ : i);     // clip [0,D]; D never matches d
}

__global__ __launch_bounds__(256) void depth_loss_fused(
        const float* __restrict__ gt, const float* __restrict__ dp,
        float* __restrict__ part, int* __restrict__ flags,
        float* __restrict__ out) {
    const int t    = blockIdx.x * 256 + threadIdx.x;
    const int hwq  = t % NHWQ_;           // quad within image plane
    const int rest = t / NHWQ_;
    const int ch   = rest % NCH_;         // which 16-slice d-chunk
    const int bn   = rest / NCH_;         // (b*N + n)
    const int hw   = hwq * 4;
    const int d0   = ch * DPC_;

    // issue gt + all 16 slice loads back-to-back
    const float4 g = *reinterpret_cast<const float4*>(gt + bn * HW_ + hw);
    const float* p = dp + ((bn * D_ + d0) * HW_ + hw);
    float4 xv[DPC_];
    #pragma unroll
    for (int i = 0; i < DPC_; ++i)
        xv[i] = *reinterpret_cast<const float4*>(p + (size_t)i * HW_);

    // keep-alive fence (R10): keeps the 16 float4s batched/live
    #pragma unroll
    for (int i = 0; i < DPC_; ++i)
        asm volatile("" :: "v"(xv[i].x), "v"(xv[i].y), "v"(xv[i].z), "v"(xv[i].w));

    const float w0 = (g.x != 0.0f) ? 1.0f : 0.0f;
    const float w1 = (g.y != 0.0f) ? 1.0f : 0.0f;
    const float w2 = (g.z != 0.0f) ? 1.0f : 0.0f;
    const float w3 = (g.w != 0.0f) ? 1.0f : 0.0f;
    const int  i0 = bucket(g.x), i1 = bucket(g.y), i2 = bucket(g.z), i3 = bucket(g.w);

    float s = 0.0f;
    #pragma unroll
    for (int i = 0; i < DPC_; ++i) {
        const int d = d0 + i;
        s += term(xv[i].x, w0, d == i0);
        s += term(xv[i].y, w1, d == i1);
        s += term(xv[i].z, w2, d == i2);
        s += term(xv[i].w, w3, d == i3);
    }

    // block reduce -> one partial per block
    #pragma unroll
    for (int off = 32; off > 0; off >>= 1) s += __shfl_down(s, off, 64);
    __shared__ float ls[4];
    if ((threadIdx.x & 63) == 0) ls[threadIdx.x >> 6] = s;
    __syncthreads();

    if (blockIdx.x != 0) {
        // publish partial, then flag; exit immediately (no scan traffic)
        if (threadIdx.x == 0) {
            __hip_atomic_store(&part[blockIdx.x], (ls[0] + ls[1]) + (ls[2] + ls[3]),
                               __ATOMIC_RELAXED, __HIP_MEMORY_SCOPE_AGENT);
            __hip_atomic_store(&flags[blockIdx.x], MAGIC_,
                               __ATOMIC_RELEASE, __HIP_MEMORY_SCOPE_AGENT);
        }
        return;
    }

    // ---- block 0: the only poller/finisher ----
    if (threadIdx.x == 0)
        part[0] = (ls[0] + ls[1]) + (ls[2] + ls[3]);

    // poll own subset (<=4 flags/thread) until all 923 peers published
    for (;;) {
        bool mine = true;
        for (int i = threadIdx.x; i < NBLK_; i += 256)
            if (i != 0)
                mine &= (__hip_atomic_load(&flags[i], __ATOMIC_RELAXED,
                                           __HIP_MEMORY_SCOPE_AGENT) == MAGIC_);
        if (__syncthreads_and(mine)) break;
        __builtin_amdgcn_s_sleep(8);     // backoff: keep coherent traffic low
    }
    __threadfence();   // acquire: order flag reads before partial reads

    float r = 0.0f;
    for (int i = threadIdx.x; i < NBLK_; i += 256)   // fixed-order -> deterministic
        r += (i == 0) ? part[0]
                      : __hip_atomic_load(&part[i], __ATOMIC_RELAXED,
                                          __HIP_MEMORY_SCOPE_AGENT);
    #pragma unroll
    for (int off = 32; off > 0; off >>= 1) r += __shfl_down(r, off, 64);
    if ((threadIdx.x & 63) == 0) ls[threadIdx.x >> 6] = r;
    __syncthreads();
    if (threadIdx.x == 0)
        out[0] = ((ls[0] + ls[1]) + (ls[2] + ls[3])) * SCALE_;

    // clear flags for the next replay (ordered before kernel-end release)
    for (int i = threadIdx.x; i < NBLK_; i += 256)
        __hip_atomic_store(&flags[i], 0, __ATOMIC_RELAXED,
                           __HIP_MEMORY_SCOPE_AGENT);
}

}  // namespace

extern "C" void kernel_launch(void* const* d_in, const int* in_sizes, int n_in,
                              void* d_out, int out_size, void* d_ws, size_t ws_size,
                              hipStream_t stream) {
    const float* gt = (const float*)d_in[0];   // depth_gt (B,N,H,W)
    const float* dp = (const float*)d_in[1];   // depth (B,N*D,H,W)
    float* part = (float*)d_ws;                // 924 floats @ ws+0
    int* flags  = (int*)((char*)d_ws + 4096);  // 924 ints  @ ws+4096
    float* out  = (float*)d_out;
    depth_loss_fused<<<NBLK_, 256, 0, stream>>>(gt, dp, part, flags, out);
}